// Round 1
// baseline (264.787 us; speedup 1.0000x reference)
//
#include <hip/hip_runtime.h>

typedef __attribute__((ext_vector_type(8))) short short8v;
typedef __attribute__((ext_vector_type(4))) float f32x4;
typedef __attribute__((ext_vector_type(4))) unsigned short us4;

#define MFMA(a,b,c) __builtin_amdgcn_mfma_f32_16x16x32_bf16(a,b,c,0,0,0)

__device__ __forceinline__ unsigned short f2b(float f){
  unsigned int u = __float_as_uint(f);
  u += 0x7fffu + ((u >> 16) & 1u);   // round-to-nearest-even
  return (unsigned short)(u >> 16);
}

__device__ __forceinline__ void gll16(const void* g, void* l){
  __builtin_amdgcn_global_load_lds((const __attribute__((address_space(1))) void*)g,
                                   (__attribute__((address_space(3))) void*)l, 16, 0, 0);
}

// ---------------- cast f32 -> bf16 (vectorized float4 -> ushort4) ----------------
__global__ __launch_bounds__(256) void cast_bf16_k(const float* __restrict__ in,
                                                   unsigned short* __restrict__ out, int n4){
  int i = blockIdx.x * 256 + threadIdx.x;
  if (i >= n4) return;
  float4 v = reinterpret_cast<const float4*>(in)[i];
  us4 o; o.x = f2b(v.x); o.y = f2b(v.y); o.z = f2b(v.z); o.w = f2b(v.w);
  reinterpret_cast<us4*>(out)[i] = o;
}

// ---------------- count[b] = sum_n mWin^2 ----------------
__global__ __launch_bounds__(256) void count_k(const float* __restrict__ mWin,
                                               float* __restrict__ cnt){
  int b = blockIdx.x;
  float s = 0.f;
  for (int i = threadIdx.x; i < 2048; i += 256){ float m = mWin[b*2048 + i]; s += m*m; }
  #pragma unroll
  for (int o = 32; o >= 1; o >>= 1) s += __shfl_xor(s, o, 64);
  if ((threadIdx.x & 63) == 0) atomicAdd(&cnt[b], s);
}

// ---------------- qkv GEMM: xb[8192x1024] @ wb[3072x1024]^T -> masked/scaled q,k,v bf16 ----------------
// q,k,v layout: [B*H][N][hd] = [64][2048][64]
__global__ __launch_bounds__(256,2) void qkv_gemm(
    const unsigned short* __restrict__ xb,
    const unsigned short* __restrict__ wb,
    const float* __restrict__ mWin,
    unsigned short* __restrict__ qb,
    unsigned short* __restrict__ kb,
    unsigned short* __restrict__ vb)
{
  __shared__ unsigned short As[128*64];
  __shared__ unsigned short Bs[128*64];
  int lin = blockIdx.x;                       // 1536 blocks
  int swz = (lin & 7) * 192 + (lin >> 3);     // XCD swizzle (1536 % 8 == 0)
  int tM = swz & 63, tN = swz >> 6;           // 64 x 24
  int tid = threadIdx.x, lane = tid & 63, wv = tid >> 6;
  int lr = lane & 15, lg = lane >> 4;

  const unsigned short* ga[4]; const unsigned short* gbp[4];
  char* lA[4]; char* lB[4];
  #pragma unroll
  for (int c = 0; c < 4; ++c){
    int o = c*4096 + wv*1024 + lane*16;       // byte offset within 16KB tile
    int row = o >> 7, cole = (o & 127) >> 1;
    ga[c]  = xb + (tM*128 + row)*1024 + cole;
    gbp[c] = wb + (tN*128 + row)*1024 + cole;
    lA[c] = (char*)As + c*4096 + wv*1024;     // wave-uniform LDS base
    lB[c] = (char*)Bs + c*4096 + wv*1024;
  }

  f32x4 acc[4][4];
  #pragma unroll
  for (int i = 0; i < 4; ++i)
    #pragma unroll
    for (int j = 0; j < 4; ++j) acc[i][j] = (f32x4){0.f,0.f,0.f,0.f};

  int wr = (wv >> 1) * 64, wc = (wv & 1) * 64;

  for (int it = 0; it < 16; ++it){
    #pragma unroll
    for (int c = 0; c < 4; ++c){
      gll16(ga[c]  + it*64, lA[c]);
      gll16(gbp[c] + it*64, lB[c]);
    }
    __syncthreads();
    short8v af[4][2], bf[4][2];
    #pragma unroll
    for (int mi = 0; mi < 4; ++mi)
      #pragma unroll
      for (int ks = 0; ks < 2; ++ks)
        af[mi][ks] = *(const short8v*)&As[(wr + mi*16 + lr)*64 + ks*32 + lg*8];
    #pragma unroll
    for (int ni = 0; ni < 4; ++ni)
      #pragma unroll
      for (int ks = 0; ks < 2; ++ks)
        bf[ni][ks] = *(const short8v*)&Bs[(wc + ni*16 + lr)*64 + ks*32 + lg*8];
    #pragma unroll
    for (int mi = 0; mi < 4; ++mi)
      #pragma unroll
      for (int ni = 0; ni < 4; ++ni)
        #pragma unroll
        for (int ks = 0; ks < 2; ++ks)
          acc[mi][ni] = MFMA(af[mi][ks], bf[ni][ks], acc[mi][ni]);
    __syncthreads();
  }

  // epilogue: scatter to q/k/v with mask (+scale for q)
  int which = tN >> 3;               // 0=q 1=k 2=v (128-col tiles never straddle)
  int c0 = (tN & 7) * 128;
  float sf = (which == 0) ? 0.125f : 1.0f;
  unsigned short* dst = (which == 0) ? qb : (which == 1) ? kb : vb;
  #pragma unroll
  for (int mi = 0; mi < 4; ++mi){
    #pragma unroll
    for (int j = 0; j < 4; ++j){
      int m = tM*128 + wr + mi*16 + lg*4 + j;      // m = b*2048 + n
      float f = sf * mWin[m];
      int b = m >> 11, n = m & 2047;
      #pragma unroll
      for (int ni = 0; ni < 4; ++ni){
        int col = c0 + wc + ni*16 + lr;            // 0..1023 within q/k/v
        int h = col >> 6, d = col & 63;
        dst[(((b << 4) + h)*2048 + n)*64 + d] = f2b(acc[mi][ni][j] * f);
      }
    }
  }
}

// ---------------- attention: per (qtile, b*h) block; one-pass softmax (no max-sub needed) ----------------
__global__ __launch_bounds__(256,2) void attn_k(
  const unsigned short* __restrict__ qbuf,
  const unsigned short* __restrict__ kbuf,
  const unsigned short* __restrict__ vbuf,
  const float* __restrict__ mWin,
  const float* __restrict__ cnt,
  unsigned short* __restrict__ ab)
{
  __shared__ unsigned short Ks[64*64];     // K tile, row-major [kk][d]
  __shared__ unsigned short Vt[64*64];     // V tile transposed [d][kk]
  __shared__ unsigned short Ps[4*32*64];   // per-wave P [32 rows][64 kk]
  int qt = blockIdx.x, bh = blockIdx.y;    // 16 x 64
  int b = bh >> 4, h = bh & 15;
  const unsigned short* Q = qbuf + (bh*2048 + qt*128)*64;
  const unsigned short* K = kbuf + bh*2048*64;
  const unsigned short* V = vbuf + bh*2048*64;
  int tid = threadIdx.x, lane = tid & 63, wv = tid >> 6;
  int lr = lane & 15, lg = lane >> 4;

  short8v qf[2][2];
  #pragma unroll
  for (int mi = 0; mi < 2; ++mi)
    #pragma unroll
    for (int ks = 0; ks < 2; ++ks)
      qf[mi][ks] = *(const short8v*)&Q[(wv*32 + mi*16 + lr)*64 + ks*32 + lg*8];

  f32x4 oacc[2][4];
  #pragma unroll
  for (int mi = 0; mi < 2; ++mi)
    #pragma unroll
    for (int nf = 0; nf < 4; ++nf) oacc[mi][nf] = (f32x4){0.f,0.f,0.f,0.f};
  float den[2][4] = {{0.f,0.f,0.f,0.f},{0.f,0.f,0.f,0.f}};

  int vk = tid & 63, vd0 = (tid >> 6) * 16;

  for (int t = 0; t < 32; ++t){
    // stage K tile (contiguous 8KB) via global_load_lds
    #pragma unroll
    for (int c = 0; c < 2; ++c){
      int o = c*4096 + wv*1024 + lane*16;
      gll16((const char*)K + t*8192 + o, (char*)Ks + c*4096 + wv*1024);
    }
    // stage V tile transposed (coalesced global read, 2-way-free LDS writes)
    {
      const unsigned short* vrow = V + (t*64 + vk)*64 + vd0;
      short8v v0 = *(const short8v*)vrow;
      short8v v1 = *(const short8v*)(vrow + 8);
      #pragma unroll
      for (int e = 0; e < 8; ++e){
        Vt[(vd0 + e)*64 + vk]     = (unsigned short)v0[e];
        Vt[(vd0 + 8 + e)*64 + vk] = (unsigned short)v1[e];
      }
    }
    __syncthreads();

    // S = Q K^T  (rows: wave's 32 q-rows; cols: 64 kk)
    short8v kf[4][2];
    #pragma unroll
    for (int ni = 0; ni < 4; ++ni)
      #pragma unroll
      for (int ks = 0; ks < 2; ++ks)
        kf[ni][ks] = *(const short8v*)&Ks[(ni*16 + lr)*64 + ks*32 + lg*8];
    f32x4 s[2][4];
    #pragma unroll
    for (int mi = 0; mi < 2; ++mi)
      #pragma unroll
      for (int ni = 0; ni < 4; ++ni){
        f32x4 sa = (f32x4){0.f,0.f,0.f,0.f};
        #pragma unroll
        for (int ks = 0; ks < 2; ++ks) sa = MFMA(qf[mi][ks], kf[ni][ks], sa);
        s[mi][ni] = sa;
      }

    // P = exp(S); accumulate den partials; write P (bf16) to per-wave LDS
    #pragma unroll
    for (int mi = 0; mi < 2; ++mi)
      #pragma unroll
      for (int ni = 0; ni < 4; ++ni)
        #pragma unroll
        for (int j = 0; j < 4; ++j){
          float p = __expf(s[mi][ni][j]);
          den[mi][j] += p;
          Ps[(wv*32 + mi*16 + lg*4 + j)*64 + ni*16 + lr] = f2b(p);
        }

    // O += P V   (A-frags from Ps, B-frags from Vt: both contiguous b128)
    short8v pf[2][2], vf[4][2];
    #pragma unroll
    for (int mi = 0; mi < 2; ++mi)
      #pragma unroll
      for (int ks = 0; ks < 2; ++ks)
        pf[mi][ks] = *(const short8v*)&Ps[(wv*32 + mi*16 + lr)*64 + ks*32 + lg*8];
    #pragma unroll
    for (int nf = 0; nf < 4; ++nf)
      #pragma unroll
      for (int ks = 0; ks < 2; ++ks)
        vf[nf][ks] = *(const short8v*)&Vt[(nf*16 + lr)*64 + ks*32 + lg*8];
    #pragma unroll
    for (int mi = 0; mi < 2; ++mi)
      #pragma unroll
      for (int nf = 0; nf < 4; ++nf)
        #pragma unroll
        for (int ks = 0; ks < 2; ++ks)
          oacc[mi][nf] = MFMA(pf[mi][ks], vf[nf][ks], oacc[mi][nf]);
    __syncthreads();
  }

  // epilogue: reduce den across 16 lanes, divide by den*(mx+1e-6), store bf16
  #pragma unroll
  for (int mi = 0; mi < 2; ++mi)
    #pragma unroll
    for (int j = 0; j < 4; ++j){
      float d = den[mi][j];
      d += __shfl_xor(d, 1, 64); d += __shfl_xor(d, 2, 64);
      d += __shfl_xor(d, 4, 64); d += __shfl_xor(d, 8, 64);
      int n = qt*128 + wv*32 + mi*16 + lg*4 + j;
      float mv = mWin[b*2048 + n];
      float g = 1.0f / (d * (mv * cnt[b] + 1e-6f));
      #pragma unroll
      for (int nf = 0; nf < 4; ++nf)
        ab[(b*2048 + n)*1024 + h*64 + nf*16 + lr] = f2b(oacc[mi][nf][j] * g);
    }
}

// ---------------- proj GEMM: ab[8192x1024] @ wproj[1024x1024]^T + bias -> fp32 out ----------------
__global__ __launch_bounds__(256,2) void proj_gemm(
    const unsigned short* __restrict__ abuf,
    const unsigned short* __restrict__ wb,
    const float* __restrict__ pb,
    float* __restrict__ out)
{
  __shared__ unsigned short As[128*64];
  __shared__ unsigned short Bs[128*64];
  int lin = blockIdx.x;                      // 512 blocks
  int swz = (lin & 7) * 64 + (lin >> 3);
  int tM = swz & 63, tN = swz >> 6;          // 64 x 8
  int tid = threadIdx.x, lane = tid & 63, wv = tid >> 6;
  int lr = lane & 15, lg = lane >> 4;

  const unsigned short* ga[4]; const unsigned short* gbp[4];
  char* lA[4]; char* lB[4];
  #pragma unroll
  for (int c = 0; c < 4; ++c){
    int o = c*4096 + wv*1024 + lane*16;
    int row = o >> 7, cole = (o & 127) >> 1;
    ga[c]  = abuf + (tM*128 + row)*1024 + cole;
    gbp[c] = wb   + (tN*128 + row)*1024 + cole;
    lA[c] = (char*)As + c*4096 + wv*1024;
    lB[c] = (char*)Bs + c*4096 + wv*1024;
  }

  f32x4 acc[4][4];
  #pragma unroll
  for (int i = 0; i < 4; ++i)
    #pragma unroll
    for (int j = 0; j < 4; ++j) acc[i][j] = (f32x4){0.f,0.f,0.f,0.f};

  int wr = (wv >> 1) * 64, wc = (wv & 1) * 64;

  for (int it = 0; it < 16; ++it){
    #pragma unroll
    for (int c = 0; c < 4; ++c){
      gll16(ga[c]  + it*64, lA[c]);
      gll16(gbp[c] + it*64, lB[c]);
    }
    __syncthreads();
    short8v af[4][2], bf[4][2];
    #pragma unroll
    for (int mi = 0; mi < 4; ++mi)
      #pragma unroll
      for (int ks = 0; ks < 2; ++ks)
        af[mi][ks] = *(const short8v*)&As[(wr + mi*16 + lr)*64 + ks*32 + lg*8];
    #pragma unroll
    for (int ni = 0; ni < 4; ++ni)
      #pragma unroll
      for (int ks = 0; ks < 2; ++ks)
        bf[ni][ks] = *(const short8v*)&Bs[(wc + ni*16 + lr)*64 + ks*32 + lg*8];
    #pragma unroll
    for (int mi = 0; mi < 4; ++mi)
      #pragma unroll
      for (int ni = 0; ni < 4; ++ni)
        #pragma unroll
        for (int ks = 0; ks < 2; ++ks)
          acc[mi][ni] = MFMA(af[mi][ks], bf[ni][ks], acc[mi][ni]);
    __syncthreads();
  }

  #pragma unroll
  for (int mi = 0; mi < 4; ++mi){
    #pragma unroll
    for (int j = 0; j < 4; ++j){
      int m = tM*128 + wr + mi*16 + lg*4 + j;
      #pragma unroll
      for (int ni = 0; ni < 4; ++ni){
        int col = tN*128 + wc + ni*16 + lr;
        out[m*1024 + col] = acc[mi][ni][j] + pb[col];
      }
    }
  }
}

extern "C" void kernel_launch(void* const* d_in, const int* in_sizes, int n_in,
                              void* d_out, int out_size, void* d_ws, size_t ws_size,
                              hipStream_t stream) {
  const float* x      = (const float*)d_in[0];
  const float* mWin   = (const float*)d_in[1];
  const float* qkv_w  = (const float*)d_in[2];
  const float* proj_w = (const float*)d_in[3];
  const float* proj_b = (const float*)d_in[4];
  float* out = (float*)d_out;
  char* ws = (char*)d_ws;

  // workspace layout (bytes); ab aliases xb (xb dead after qkv_gemm)
  unsigned short* xb     = (unsigned short*)(ws);                 // 16 MB
  unsigned short* ab     = (unsigned short*)(ws);                 // alias
  unsigned short* wqkvb  = (unsigned short*)(ws + 16777216);      //  6 MB
  unsigned short* wprojb = (unsigned short*)(ws + 23068672);      //  2 MB
  unsigned short* qb     = (unsigned short*)(ws + 25165824);      // 16 MB
  unsigned short* kb     = (unsigned short*)(ws + 41943040);      // 16 MB
  unsigned short* vb     = (unsigned short*)(ws + 58720256);      // 16 MB
  float* cnt             = (float*)(ws + 75497472);               // 16 B

  hipMemsetAsync(cnt, 0, 16, stream);
  cast_bf16_k<<<2097152/256, 256, 0, stream>>>(x,      xb,     2097152);
  cast_bf16_k<<< 786432/256, 256, 0, stream>>>(qkv_w,  wqkvb,   786432);
  cast_bf16_k<<< 262144/256, 256, 0, stream>>>(proj_w, wprojb,  262144);
  count_k<<<4, 256, 0, stream>>>(mWin, cnt);
  qkv_gemm<<<1536, 256, 0, stream>>>(xb, wqkvb, mWin, qb, kb, vb);
  attn_k<<<dim3(16, 64), 256, 0, stream>>>(qb, kb, vb, mWin, cnt, ab);
  proj_gemm<<<512, 256, 0, stream>>>(ab, wprojb, proj_b, out);
}

// Round 2
// 241.522 us; speedup vs baseline: 1.0963x; 1.0963x over previous
//
#include <hip/hip_runtime.h>

typedef __attribute__((ext_vector_type(8))) short short8v;
typedef __attribute__((ext_vector_type(4))) float f32x4;
typedef __attribute__((ext_vector_type(4))) unsigned short us4;

#define MFMA(a,b,c) __builtin_amdgcn_mfma_f32_16x16x32_bf16(a,b,c,0,0,0)

__device__ __forceinline__ unsigned short f2b(float f){
  unsigned int u = __float_as_uint(f);
  u += 0x7fffu + ((u >> 16) & 1u);   // round-to-nearest-even
  return (unsigned short)(u >> 16);
}

__device__ __forceinline__ void gll16(const void* g, void* l){
  __builtin_amdgcn_global_load_lds((const __attribute__((address_space(1))) void*)g,
                                   (__attribute__((address_space(3))) void*)l, 16, 0, 0);
}

// swizzled LDS read pointer for [rows][128B] tiles: byte = row*128 + inrow, ^ (row&7)<<4
__device__ __forceinline__ const short8v* swz16(const void* base, int row, int inrow){
  int byte = (row * 128 + inrow) ^ ((row & 7) << 4);
  return (const short8v*)((const char*)base + byte);
}

// ---------------- cast f32 -> bf16 (vectorized float4 -> ushort4) ----------------
__global__ __launch_bounds__(256) void cast_bf16_k(const float* __restrict__ in,
                                                   unsigned short* __restrict__ out, int n4){
  int i = blockIdx.x * 256 + threadIdx.x;
  if (i >= n4) return;
  float4 v = reinterpret_cast<const float4*>(in)[i];
  us4 o; o.x = f2b(v.x); o.y = f2b(v.y); o.z = f2b(v.z); o.w = f2b(v.w);
  reinterpret_cast<us4*>(out)[i] = o;
}

// ---------------- count[b] = sum_n mWin^2 ----------------
__global__ __launch_bounds__(256) void count_k(const float* __restrict__ mWin,
                                               float* __restrict__ cnt){
  int b = blockIdx.x;
  float s = 0.f;
  for (int i = threadIdx.x; i < 2048; i += 256){ float m = mWin[b*2048 + i]; s += m*m; }
  #pragma unroll
  for (int o = 32; o >= 1; o >>= 1) s += __shfl_xor(s, o, 64);
  if ((threadIdx.x & 63) == 0) atomicAdd(&cnt[b], s);
}

// ---------------- qkv GEMM: xb[8192x1024] @ wb[3072x1024]^T -> masked/scaled q,k,v bf16 ----------------
// q,k layout: [B*H][N][hd] = [64][2048][64]; v layout TRANSPOSED: [B*H][hd][N] = [64][64][2048]
__global__ __launch_bounds__(256,2) void qkv_gemm(
    const unsigned short* __restrict__ xb,
    const unsigned short* __restrict__ wb,
    const float* __restrict__ mWin,
    unsigned short* __restrict__ qb,
    unsigned short* __restrict__ kb,
    unsigned short* __restrict__ vb)
{
  __shared__ unsigned short As[128*64];
  __shared__ unsigned short Bs[128*64];
  int lin = blockIdx.x;                       // 1536 blocks
  int swz = (lin & 7) * 192 + (lin >> 3);     // XCD swizzle (1536 % 8 == 0)
  int tM = swz & 63, tN = swz >> 6;           // 64 x 24
  int tid = threadIdx.x, lane = tid & 63, wv = tid >> 6;
  int lr = lane & 15, lg = lane >> 4;

  const unsigned short* ga[4]; const unsigned short* gbp[4];
  char* lA[4]; char* lB[4];
  #pragma unroll
  for (int c = 0; c < 4; ++c){
    int o = c*4096 + wv*1024 + lane*16;       // byte offset within 16KB tile
    int row = o >> 7, cole = (o & 127) >> 1;
    ga[c]  = xb + (tM*128 + row)*1024 + cole;
    gbp[c] = wb + (tN*128 + row)*1024 + cole;
    lA[c] = (char*)As + c*4096 + wv*1024;     // wave-uniform LDS base
    lB[c] = (char*)Bs + c*4096 + wv*1024;
  }

  f32x4 acc[4][4];
  #pragma unroll
  for (int i = 0; i < 4; ++i)
    #pragma unroll
    for (int j = 0; j < 4; ++j) acc[i][j] = (f32x4){0.f,0.f,0.f,0.f};

  int wr = (wv >> 1) * 64, wc = (wv & 1) * 64;

  for (int it = 0; it < 16; ++it){
    #pragma unroll
    for (int c = 0; c < 4; ++c){
      gll16(ga[c]  + it*64, lA[c]);
      gll16(gbp[c] + it*64, lB[c]);
    }
    __syncthreads();
    short8v af[4][2], bf[4][2];
    #pragma unroll
    for (int mi = 0; mi < 4; ++mi)
      #pragma unroll
      for (int ks = 0; ks < 2; ++ks)
        af[mi][ks] = *(const short8v*)&As[(wr + mi*16 + lr)*64 + ks*32 + lg*8];
    #pragma unroll
    for (int ni = 0; ni < 4; ++ni)
      #pragma unroll
      for (int ks = 0; ks < 2; ++ks)
        bf[ni][ks] = *(const short8v*)&Bs[(wc + ni*16 + lr)*64 + ks*32 + lg*8];
    #pragma unroll
    for (int mi = 0; mi < 4; ++mi)
      #pragma unroll
      for (int ni = 0; ni < 4; ++ni)
        #pragma unroll
        for (int ks = 0; ks < 2; ++ks)
          acc[mi][ni] = MFMA(af[mi][ks], bf[ni][ks], acc[mi][ni]);
    __syncthreads();
  }

  // epilogue: scatter to q/k/v with mask (+scale for q); v stored transposed
  int which = tN >> 3;               // 0=q 1=k 2=v (128-col tiles never straddle)
  int c0 = (tN & 7) * 128;
  if (which == 2){
    #pragma unroll
    for (int mi = 0; mi < 4; ++mi){
      int m0 = tM*128 + wr + mi*16 + lg*4;     // m = b*2048 + n, 4 consecutive rows
      int b = m0 >> 11, n0 = m0 & 2047;
      float f0 = mWin[m0], f1 = mWin[m0+1], f2 = mWin[m0+2], f3 = mWin[m0+3];
      #pragma unroll
      for (int ni = 0; ni < 4; ++ni){
        int col = c0 + wc + ni*16 + lr;
        int h = col >> 6, d = col & 63;
        us4 o;
        o.x = f2b(acc[mi][ni][0] * f0); o.y = f2b(acc[mi][ni][1] * f1);
        o.z = f2b(acc[mi][ni][2] * f2); o.w = f2b(acc[mi][ni][3] * f3);
        *(us4*)&vb[(((b << 4) + h)*64 + d)*2048 + n0] = o;
      }
    }
  } else {
    float sf = (which == 0) ? 0.125f : 1.0f;
    unsigned short* dst = (which == 0) ? qb : kb;
    #pragma unroll
    for (int mi = 0; mi < 4; ++mi){
      #pragma unroll
      for (int j = 0; j < 4; ++j){
        int m = tM*128 + wr + mi*16 + lg*4 + j;
        float f = sf * mWin[m];
        int b = m >> 11, n = m & 2047;
        #pragma unroll
        for (int ni = 0; ni < 4; ++ni){
          int col = c0 + wc + ni*16 + lr;
          int h = col >> 6, d = col & 63;
          dst[(((b << 4) + h)*2048 + n)*64 + d] = f2b(acc[mi][ni][j] * f);
        }
      }
    }
  }
}

// ---------------- attention: swizzled LDS, double-buffered gll16 staging, 1 barrier/tile ----------------
__global__ __launch_bounds__(256,2) void attn_k(
  const unsigned short* __restrict__ qbuf,
  const unsigned short* __restrict__ kbuf,
  const unsigned short* __restrict__ vbuf,   // transposed [bh][d][n]
  const float* __restrict__ mWin,
  const float* __restrict__ cnt,
  unsigned short* __restrict__ ab)
{
  __shared__ unsigned short Ks[2][4096];    // [buf][64 kk][64 d] swizzled
  __shared__ unsigned short Vt[2][4096];    // [buf][64 d][64 kk] swizzled
  __shared__ unsigned short Ps[128*64];     // [128 q][64 kk] swizzled
  int qt = blockIdx.x, bh = blockIdx.y;     // 16 x 64
  int b = bh >> 4, h = bh & 15;
  const unsigned short* Q  = qbuf + (bh*2048 + qt*128)*64;
  const char* Kg = (const char*)(kbuf + bh*2048*64);      // rows n, 128B, contiguous
  const char* Vg = (const char*)(vbuf + bh*64*2048);      // rows d, 4096B stride
  int tid = threadIdx.x, lane = tid & 63, wv = tid >> 6;
  int lr = lane & 15, lg = lane >> 4;

  // staging geometry: per wave 2 rounds of 1KB; pre-swizzled global source (rule 21)
  int so[2], srow[2];
  #pragma unroll
  for (int r = 0; r < 2; ++r){
    int o = r*4096 + wv*1024 + lane*16;
    srow[r] = o >> 7;
    so[r] = (o & 127) ^ ((srow[r] & 7) << 4);
  }

  short8v qf[2][2];
  #pragma unroll
  for (int mi = 0; mi < 2; ++mi)
    #pragma unroll
    for (int ks = 0; ks < 2; ++ks)
      qf[mi][ks] = *(const short8v*)&Q[(wv*32 + mi*16 + lr)*64 + ks*32 + lg*8];

  f32x4 oacc[2][4];
  #pragma unroll
  for (int mi = 0; mi < 2; ++mi)
    #pragma unroll
    for (int nf = 0; nf < 4; ++nf) oacc[mi][nf] = (f32x4){0.f,0.f,0.f,0.f};
  float den[2][4] = {{0.f,0.f,0.f,0.f},{0.f,0.f,0.f,0.f}};

  // prologue: stage tile 0 into buf 0
  #pragma unroll
  for (int r = 0; r < 2; ++r){
    gll16(Kg + srow[r]*128  + so[r],          (char*)Ks[0] + r*4096 + wv*1024);
    gll16(Vg + srow[r]*4096 + so[r],          (char*)Vt[0] + r*4096 + wv*1024);
  }
  __syncthreads();

  for (int t = 0; t < 32; ++t){
    int cur = t & 1, nxt = cur ^ 1;
    if (t < 31){
      #pragma unroll
      for (int r = 0; r < 2; ++r){
        gll16(Kg + (t+1)*8192 + srow[r]*128 + so[r], (char*)Ks[nxt] + r*4096 + wv*1024);
        gll16(Vg + srow[r]*4096 + (t+1)*128 + so[r], (char*)Vt[nxt] + r*4096 + wv*1024);
      }
    }

    // S = Q K^T
    short8v kf[4][2];
    #pragma unroll
    for (int ni = 0; ni < 4; ++ni)
      #pragma unroll
      for (int ks = 0; ks < 2; ++ks)
        kf[ni][ks] = *swz16(Ks[cur], ni*16 + lr, ks*64 + lg*16);
    f32x4 s[2][4];
    __builtin_amdgcn_s_setprio(1);
    #pragma unroll
    for (int mi = 0; mi < 2; ++mi)
      #pragma unroll
      for (int ni = 0; ni < 4; ++ni){
        f32x4 sa = (f32x4){0.f,0.f,0.f,0.f};
        #pragma unroll
        for (int ks = 0; ks < 2; ++ks) sa = MFMA(qf[mi][ks], kf[ni][ks], sa);
        s[mi][ni] = sa;
      }
    __builtin_amdgcn_s_setprio(0);

    // P = exp(S); den partials; write P bf16 to swizzled per-wave LDS
    #pragma unroll
    for (int mi = 0; mi < 2; ++mi)
      #pragma unroll
      for (int ni = 0; ni < 4; ++ni)
        #pragma unroll
        for (int j = 0; j < 4; ++j){
          float p = __expf(s[mi][ni][j]);
          den[mi][j] += p;
          int prow = wv*32 + mi*16 + lg*4 + j;
          int pbyt = (prow*128 + (ni*16 + lr)*2) ^ ((prow & 7) << 4);
          *(unsigned short*)((char*)Ps + pbyt) = f2b(p);
        }

    // O += P V
    short8v pf[2][2], vf[4][2];
    #pragma unroll
    for (int mi = 0; mi < 2; ++mi)
      #pragma unroll
      for (int ks = 0; ks < 2; ++ks)
        pf[mi][ks] = *swz16(Ps, wv*32 + mi*16 + lr, ks*64 + lg*16);
    #pragma unroll
    for (int nf = 0; nf < 4; ++nf)
      #pragma unroll
      for (int ks = 0; ks < 2; ++ks)
        vf[nf][ks] = *swz16(Vt[cur], nf*16 + lr, ks*64 + lg*16);
    __builtin_amdgcn_s_setprio(1);
    #pragma unroll
    for (int mi = 0; mi < 2; ++mi)
      #pragma unroll
      for (int nf = 0; nf < 4; ++nf)
        #pragma unroll
        for (int ks = 0; ks < 2; ++ks)
          oacc[mi][nf] = MFMA(pf[mi][ks], vf[nf][ks], oacc[mi][nf]);
    __builtin_amdgcn_s_setprio(0);

    __syncthreads();   // drains vmcnt (next tile staged) + guards buf reuse
  }

  // epilogue: reduce den across 16 lanes, divide by den*(mx+1e-6), store bf16
  #pragma unroll
  for (int mi = 0; mi < 2; ++mi)
    #pragma unroll
    for (int j = 0; j < 4; ++j){
      float d = den[mi][j];
      d += __shfl_xor(d, 1, 64); d += __shfl_xor(d, 2, 64);
      d += __shfl_xor(d, 4, 64); d += __shfl_xor(d, 8, 64);
      int n = qt*128 + wv*32 + mi*16 + lg*4 + j;
      float mv = mWin[b*2048 + n];
      float g = 1.0f / (d * (mv * cnt[b] + 1e-6f));
      #pragma unroll
      for (int nf = 0; nf < 4; ++nf)
        ab[(b*2048 + n)*1024 + h*64 + nf*16 + lr] = f2b(oacc[mi][nf][j] * g);
    }
}

// ---------------- proj GEMM: ab[8192x1024] @ wproj[1024x1024]^T + bias -> fp32 out ----------------
__global__ __launch_bounds__(256,2) void proj_gemm(
    const unsigned short* __restrict__ abuf,
    const unsigned short* __restrict__ wb,
    const float* __restrict__ pb,
    float* __restrict__ out)
{
  __shared__ unsigned short As[128*64];
  __shared__ unsigned short Bs[128*64];
  int lin = blockIdx.x;                      // 512 blocks
  int swz = (lin & 7) * 64 + (lin >> 3);
  int tM = swz & 63, tN = swz >> 6;          // 64 x 8
  int tid = threadIdx.x, lane = tid & 63, wv = tid >> 6;
  int lr = lane & 15, lg = lane >> 4;

  const unsigned short* ga[4]; const unsigned short* gbp[4];
  char* lA[4]; char* lB[4];
  #pragma unroll
  for (int c = 0; c < 4; ++c){
    int o = c*4096 + wv*1024 + lane*16;
    int row = o >> 7, cole = (o & 127) >> 1;
    ga[c]  = abuf + (tM*128 + row)*1024 + cole;
    gbp[c] = wb   + (tN*128 + row)*1024 + cole;
    lA[c] = (char*)As + c*4096 + wv*1024;
    lB[c] = (char*)Bs + c*4096 + wv*1024;
  }

  f32x4 acc[4][4];
  #pragma unroll
  for (int i = 0; i < 4; ++i)
    #pragma unroll
    for (int j = 0; j < 4; ++j) acc[i][j] = (f32x4){0.f,0.f,0.f,0.f};

  int wr = (wv >> 1) * 64, wc = (wv & 1) * 64;

  for (int it = 0; it < 16; ++it){
    #pragma unroll
    for (int c = 0; c < 4; ++c){
      gll16(ga[c]  + it*64, lA[c]);
      gll16(gbp[c] + it*64, lB[c]);
    }
    __syncthreads();
    short8v af[4][2], bf[4][2];
    #pragma unroll
    for (int mi = 0; mi < 4; ++mi)
      #pragma unroll
      for (int ks = 0; ks < 2; ++ks)
        af[mi][ks] = *(const short8v*)&As[(wr + mi*16 + lr)*64 + ks*32 + lg*8];
    #pragma unroll
    for (int ni = 0; ni < 4; ++ni)
      #pragma unroll
      for (int ks = 0; ks < 2; ++ks)
        bf[ni][ks] = *(const short8v*)&Bs[(wc + ni*16 + lr)*64 + ks*32 + lg*8];
    #pragma unroll
    for (int mi = 0; mi < 4; ++mi)
      #pragma unroll
      for (int ni = 0; ni < 4; ++ni)
        #pragma unroll
        for (int ks = 0; ks < 2; ++ks)
          acc[mi][ni] = MFMA(af[mi][ks], bf[ni][ks], acc[mi][ni]);
    __syncthreads();
  }

  #pragma unroll
  for (int mi = 0; mi < 4; ++mi){
    #pragma unroll
    for (int j = 0; j < 4; ++j){
      int m = tM*128 + wr + mi*16 + lg*4 + j;
      #pragma unroll
      for (int ni = 0; ni < 4; ++ni){
        int col = tN*128 + wc + ni*16 + lr;
        out[m*1024 + col] = acc[mi][ni][j] + pb[col];
      }
    }
  }
}

extern "C" void kernel_launch(void* const* d_in, const int* in_sizes, int n_in,
                              void* d_out, int out_size, void* d_ws, size_t ws_size,
                              hipStream_t stream) {
  const float* x      = (const float*)d_in[0];
  const float* mWin   = (const float*)d_in[1];
  const float* qkv_w  = (const float*)d_in[2];
  const float* proj_w = (const float*)d_in[3];
  const float* proj_b = (const float*)d_in[4];
  float* out = (float*)d_out;
  char* ws = (char*)d_ws;

  // workspace layout (bytes); ab aliases xb (xb dead after qkv_gemm)
  unsigned short* xb     = (unsigned short*)(ws);                 // 16 MB
  unsigned short* ab     = (unsigned short*)(ws);                 // alias
  unsigned short* wqkvb  = (unsigned short*)(ws + 16777216);      //  6 MB
  unsigned short* wprojb = (unsigned short*)(ws + 23068672);      //  2 MB
  unsigned short* qb     = (unsigned short*)(ws + 25165824);      // 16 MB
  unsigned short* kb     = (unsigned short*)(ws + 41943040);      // 16 MB
  unsigned short* vb     = (unsigned short*)(ws + 58720256);      // 16 MB (transposed)
  float* cnt             = (float*)(ws + 75497472);               // 16 B

  hipMemsetAsync(cnt, 0, 16, stream);
  cast_bf16_k<<<2097152/256, 256, 0, stream>>>(x,      xb,     2097152);
  cast_bf16_k<<< 786432/256, 256, 0, stream>>>(qkv_w,  wqkvb,   786432);
  cast_bf16_k<<< 262144/256, 256, 0, stream>>>(proj_w, wprojb,  262144);
  count_k<<<4, 256, 0, stream>>>(mWin, cnt);
  qkv_gemm<<<1536, 256, 0, stream>>>(xb, wqkvb, mWin, qb, kb, vb);
  attn_k<<<dim3(16, 64), 256, 0, stream>>>(qb, kb, vb, mWin, cnt, ab);
  proj_gemm<<<512, 256, 0, stream>>>(ab, wprojb, proj_b, out);
}